// Round 10
// baseline (938.169 us; speedup 1.0000x reference)
//
#include <hip/hip_runtime.h>
#include <hip/hip_cooperative_groups.h>
#include <cstdint>

// DynamicConvAttention: B=4, S=2048, D=1024, NH=16, K=3. f32 I/O, bf16 MFMA.
// Primary: ONE cooperative kernel, 7 phases, 6 grid syncs (was 7 launches).
// Fallback: round-9 7-launch path if cooperative launch is rejected.
//
// ws (73 MB): wT[0,8M) qkvb[8M,+12K) Q[9,25M) K[25,41M) V[41,57M) Pw[57,73M)
// d_out (33.5 MB f32): xb[0,16.8M) (dead after QKV -> P b0,1), vt[+16.8M)
// Lifetimes: conv->Vb only AFTER V^T (phase2); P over dead xb (phase2+).

namespace cg = cooperative_groups;

#define DEV __device__ __forceinline__

typedef unsigned short u16;
typedef __attribute__((ext_vector_type(8))) short bf16x8;
typedef __attribute__((ext_vector_type(4))) float f32x4;

static const int Sn = 2048, Dn = 1024;
static const long PBS = (long)Sn * Sn;

DEV float bf2f(u16 u) { union { unsigned int i; float f; } w; w.i = ((unsigned int)u) << 16; return w.f; }
DEV u16 f2bf(float f) {
  union { float f; unsigned int i; } w; w.f = f;
  unsigned int x = w.i;
  return (u16)((x + 0x7FFFu + ((x >> 16) & 1u)) >> 16);
}

DEV void gload_lds16(const u16* gsrc, u16* lds_dst) {
  __builtin_amdgcn_global_load_lds(
      (const __attribute__((address_space(1))) void*)gsrc,
      (__attribute__((address_space(3))) void*)lds_dst,
      16, 0, 0);
}

DEV float block_allreduce_sum(float v, float* red, int tid) {
  #pragma unroll
  for (int o = 32; o > 0; o >>= 1) v += __shfl_down(v, o, 64);
  __syncthreads();
  if ((tid & 63) == 0) red[tid >> 6] = v;
  __syncthreads();
  return red[0] + red[1] + red[2] + red[3];
}

DEV float block_allreduce_max(float v, float* red, int tid) {
  #pragma unroll
  for (int o = 32; o > 0; o >>= 1) v = fmaxf(v, __shfl_down(v, o, 64));
  __syncthreads();
  if ((tid & 63) == 0) red[tid >> 6] = v;
  __syncthreads();
  return fmaxf(fmaxf(red[0], red[1]), fmaxf(red[2], red[3]));
}

// ---- layernorm row (torch-style ddof=1, eps on std); in-place safe ----
DEV void ln_row(const u16* __restrict__ a, const u16* __restrict__ b2,
                const float* __restrict__ gamma, const float* __restrict__ beta,
                u16* __restrict__ out, long row, int tid, float* red) {
  long base = row * Dn + tid * 4;
  ushort4 av = *(const ushort4*)&a[base];
  float v0 = bf2f(av.x), v1 = bf2f(av.y), v2 = bf2f(av.z), v3 = bf2f(av.w);
  if (b2) {
    ushort4 bv4 = *(const ushort4*)&b2[base];
    v0 += bf2f(bv4.x); v1 += bf2f(bv4.y); v2 += bf2f(bv4.z); v3 += bf2f(bv4.w);
  }
  float s = block_allreduce_sum(v0 + v1 + v2 + v3, red, tid);
  float mean = s * (1.0f / 1024.0f);
  float d0 = v0 - mean, d1 = v1 - mean, d2 = v2 - mean, d3 = v3 - mean;
  float sq = block_allreduce_sum(d0 * d0 + d1 * d1 + d2 * d2 + d3 * d3, red, tid);
  float inv = 1.0f / (sqrtf(sq * (1.0f / 1023.0f)) + 1e-6f);
  float4 gv = *(const float4*)&gamma[tid * 4];
  float4 bev = *(const float4*)&beta[tid * 4];
  ushort4 o;
  o.x = f2bf(gv.x * d0 * inv + bev.x);
  o.y = f2bf(gv.y * d1 * inv + bev.y);
  o.z = f2bf(gv.z * d2 * inv + bev.z);
  o.w = f2bf(gv.w * d3 * inv + bev.w);
  *(ushort4*)&out[base] = o;
}

// ---- softmax row of 2048 bf16, in place ----
DEV void softmax_row(u16* __restrict__ p, int tid, float* red) {
  ushort4 a = *(const ushort4*)&p[tid * 8];
  ushort4 b = *(const ushort4*)&p[tid * 8 + 4];
  float f0 = bf2f(a.x), f1 = bf2f(a.y), f2 = bf2f(a.z), f3 = bf2f(a.w);
  float f4 = bf2f(b.x), f5 = bf2f(b.y), f6 = bf2f(b.z), f7 = bf2f(b.w);
  float m = fmaxf(fmaxf(fmaxf(f0, f1), fmaxf(f2, f3)),
                  fmaxf(fmaxf(f4, f5), fmaxf(f6, f7)));
  m = block_allreduce_max(m, red, tid);
  float e0 = __expf(f0 - m), e1 = __expf(f1 - m), e2 = __expf(f2 - m), e3 = __expf(f3 - m);
  float e4 = __expf(f4 - m), e5 = __expf(f5 - m), e6 = __expf(f6 - m), e7 = __expf(f7 - m);
  float s = block_allreduce_sum(e0 + e1 + e2 + e3 + e4 + e5 + e6 + e7, red, tid);
  float inv = 1.0f / s;
  ushort4 o1, o2;
  o1.x = f2bf(e0 * inv); o1.y = f2bf(e1 * inv); o1.z = f2bf(e2 * inv); o1.w = f2bf(e3 * inv);
  o2.x = f2bf(e4 * inv); o2.y = f2bf(e5 * inv); o2.z = f2bf(e6 * inv); o2.w = f2bf(e7 * inv);
  *(ushort4*)&p[tid * 8] = o1;
  *(ushort4*)&p[tid * 8 + 4] = o2;
}

// ---- GEMM tile (r7 core): 128x128, BK=64 split-halves, global_load_lds ----
// smem: sA = sm, sB = sm + 8192 (u16 units). Ends with __syncthreads.
template<typename CT>
DEV void gemm_tile(u16* sm, int tid,
                   const u16* __restrict__ A, int lda,
                   const u16* __restrict__ B, int ldb,
                   CT* __restrict__ C, int ldc,
                   long m0, long n0, int K, float scale,
                   const float* __restrict__ bias,
                   const float* __restrict__ res, int ldr) {
  u16* sA = sm;
  u16* sB = sm + 8192;
  int lane = tid & 63, wv = tid >> 6;
  int quad = lane >> 4, lm = lane & 15;
  int wr = wv >> 1, wc = wv & 1;
  f32x4 acc[4][4] = {};
  int srow = wv * 16 + (lane >> 2);
  int sch = (lane & 3) * 8;
  const u16* Ap = A + (m0 + srow) * (long)lda + sch;
  const u16* Bp = B + (n0 + srow) * (long)ldb + sch;
  const int lofs = wv * 16 * 32;

  for (int k0 = 0; k0 < K; k0 += 64) {
    #pragma unroll
    for (int h = 0; h < 2; h++) {
      int kh = k0 + h * 32;
      gload_lds16(Ap + kh, &sA[h * 4096 + lofs]);
      gload_lds16(Ap + 64 * (long)lda + kh, &sA[h * 4096 + lofs + 64 * 32]);
      gload_lds16(Bp + kh, &sB[h * 4096 + lofs]);
      gload_lds16(Bp + 64 * (long)ldb + kh, &sB[h * 4096 + lofs + 64 * 32]);
    }
    __syncthreads();
    #pragma unroll
    for (int h = 0; h < 2; h++) {
      bf16x8 af[4], bfr[4];
      #pragma unroll
      for (int mi = 0; mi < 4; mi++)
        af[mi] = *(const bf16x8*)&sA[h * 4096 + (wr * 64 + mi * 16 + lm) * 32 + quad * 8];
      #pragma unroll
      for (int ni = 0; ni < 4; ni++)
        bfr[ni] = *(const bf16x8*)&sB[h * 4096 + (wc * 64 + ni * 16 + lm) * 32 + quad * 8];
      #pragma unroll
      for (int mi = 0; mi < 4; mi++)
        #pragma unroll
        for (int ni = 0; ni < 4; ni++)
          acc[mi][ni] = __builtin_amdgcn_mfma_f32_16x16x32_bf16(af[mi], bfr[ni], acc[mi][ni], 0, 0, 0);
    }
    __syncthreads();
  }
  // C/D layout: col=lane&15, row=quad*4+reg (m89/m91)
  #pragma unroll
  for (int mi = 0; mi < 4; mi++) {
    #pragma unroll
    for (int ni = 0; ni < 4; ni++) {
      int col = (int)n0 + wc * 64 + ni * 16 + lm;
      float bv = bias ? bias[col] : 0.0f;
      #pragma unroll
      for (int r = 0; r < 4; r++) {
        long rowg = m0 + wr * 64 + mi * 16 + quad * 4 + r;
        float v = acc[mi][ni][r] * scale + bv;
        if (res) v += res[rowg * (long)ldr + col];
        if constexpr (sizeof(CT) == 2) C[rowg * (long)ldc + col] = f2bf(v);
        else                           C[rowg * (long)ldc + col] = v;
      }
    }
  }
}

// ---- weight transpose+cvt task (tile t of 4x256); trailing sync ----
DEV void wtr_task(u16* sm_, int tid, int t4,
                  const float* __restrict__ Wq, const float* __restrict__ Wk,
                  const float* __restrict__ Wv, const float* __restrict__ Wo,
                  u16* __restrict__ wT) {
  u16 (*sm)[68] = (u16(*)[68])sm_;
  int w = t4 >> 8, t = t4 & 255;
  const float* src = (w == 0) ? Wq : (w == 1) ? Wk : (w == 2) ? Wv : Wo;
  u16* dst = wT + (size_t)w * 1048576u;
  int i0 = (t >> 4) << 6, j0 = (t & 15) << 6;
  int tx = tid & 15, r0 = tid >> 4;
  #pragma unroll
  for (int rr = r0; rr < 64; rr += 16) {
    float4 v = *(const float4*)&src[(long)(i0 + rr) * 1024 + j0 + tx * 4];
    sm[rr][tx*4+0] = f2bf(v.x); sm[rr][tx*4+1] = f2bf(v.y);
    sm[rr][tx*4+2] = f2bf(v.z); sm[rr][tx*4+3] = f2bf(v.w);
  }
  __syncthreads();
  #pragma unroll
  for (int cc = r0; cc < 64; cc += 16) {
    ushort4 o;
    o.x = sm[tx*4+0][cc]; o.y = sm[tx*4+1][cc];
    o.z = sm[tx*4+2][cc]; o.w = sm[tx*4+3][cc];
    *(ushort4*)&dst[(long)(j0 + cc) * 1024 + i0 + tx * 4] = o;
  }
  __syncthreads();
}

// ---- V^T 64x64 tile task; trailing sync ----
DEV void vt_task(u16* sm_, int tid, int tt,
                 const u16* __restrict__ Vb, u16* __restrict__ vt) {
  u16 (*sm)[68] = (u16(*)[68])sm_;
  int b = tt >> 9, r = tt & 511;
  int j0 = (r & 15) << 6, i0 = ((r >> 4) & 31) << 6;
  const u16* s = Vb + (long)b * Sn * Dn;
  u16* d = vt + (long)b * Dn * Sn;
  int tx = tid & 15, r0 = tid >> 4;
  #pragma unroll
  for (int rr = r0; rr < 64; rr += 16) {
    ushort4 v = *(const ushort4*)&s[(long)(i0 + rr) * 1024 + j0 + tx * 4];
    sm[rr][tx*4+0] = v.x; sm[rr][tx*4+1] = v.y; sm[rr][tx*4+2] = v.z; sm[rr][tx*4+3] = v.w;
  }
  __syncthreads();
  #pragma unroll
  for (int cc = r0; cc < 64; cc += 16) {
    ushort4 o;
    o.x = sm[tx*4+0][cc]; o.y = sm[tx*4+1][cc];
    o.z = sm[tx*4+2][cc]; o.w = sm[tx*4+3][cc];
    *(ushort4*)&d[(long)(j0 + cc) * 2048 + i0 + tx * 4] = o;
  }
  __syncthreads();
}

// ---- grouped conv MFMA task (reads x,cw f32); trailing sync ----
DEV void conv_task(u16* smem, int tid, int r,
                   const float* __restrict__ x, const float* __restrict__ cw,
                   const float* __restrict__ cb, u16* __restrict__ convo) {
  u16 (*sx)[72] = (u16(*)[72])smem;              // 130x72 = 9360 u16
  u16 (*sw)[200] = (u16(*)[200])(smem + 9360);   // 64x200 = 12800 u16
  int s0 = (r & 15) * 128;
  int g = (r >> 4) & 15;
  int b = r >> 8;
  int lane = tid & 63, wv = tid >> 6;
  int quad = lane >> 4, lm = lane & 15;
  for (int idx = tid; idx < 64 * 192; idx += 256) {
    int oc = idx / 192, k = idx - oc * 192;
    int t = k >> 6, i = k & 63;
    sw[oc][k] = f2bf(cw[((long)(g * 64 + oc)) * 192 + i * 3 + t]);
  }
  for (int idx = tid; idx < 130 * 16; idx += 256) {
    int rr = idx >> 4, c4 = (idx & 15) * 4;
    int s = s0 - 1 + rr;
    ushort4 v;
    if (s >= 0 && s < Sn) {
      float4 f = *(const float4*)&x[((long)b * Sn + s) * Dn + g * 64 + c4];
      v.x = f2bf(f.x); v.y = f2bf(f.y); v.z = f2bf(f.z); v.w = f2bf(f.w);
    } else { v.x = 0; v.y = 0; v.z = 0; v.w = 0; }
    *(ushort4*)&sx[rr][c4] = v;
  }
  __syncthreads();
  f32x4 acc[2][4] = {};
  #pragma unroll
  for (int ks = 0; ks < 6; ks++) {
    int t = ks >> 1;
    int i0 = (ks & 1) * 32 + quad * 8;
    bf16x8 a0 = *(const bf16x8*)&sx[wv * 32 + lm + t][i0];
    bf16x8 a1 = *(const bf16x8*)&sx[wv * 32 + 16 + lm + t][i0];
    #pragma unroll
    for (int nf = 0; nf < 4; nf++) {
      bf16x8 bf = *(const bf16x8*)&sw[nf * 16 + lm][ks * 32 + quad * 8];
      acc[0][nf] = __builtin_amdgcn_mfma_f32_16x16x32_bf16(a0, bf, acc[0][nf], 0, 0, 0);
      acc[1][nf] = __builtin_amdgcn_mfma_f32_16x16x32_bf16(a1, bf, acc[1][nf], 0, 0, 0);
    }
  }
  #pragma unroll
  for (int mi = 0; mi < 2; mi++) {
    #pragma unroll
    for (int nf = 0; nf < 4; nf++) {
      int col = g * 64 + nf * 16 + lm;
      float bias = cb[col];
      #pragma unroll
      for (int rr = 0; rr < 4; rr++) {
        int row = wv * 32 + mi * 16 + quad * 4 + rr;
        convo[((long)b * Sn + s0 + row) * Dn + col] = f2bf(acc[mi][nf][rr] + bias);
      }
    }
  }
  __syncthreads();
}

// ================= cooperative mega kernel =================
struct MegaP {
  const float *x, *Wq, *bq, *Wk, *Wv, *bv, *cw, *cb, *gamma, *beta, *Wo, *bo;
  u16 *wT; float *qkvb;
  u16 *Qb, *Kb, *Vb, *Pw, *xb, *Pd, *vt, *conv, *attn, *combined;
  float *out;
};

__global__ __launch_bounds__(256, 3)
void mega(MegaP P) {
  __shared__ u16 smem[22168];   // 44.3 KB: max(gemm 16384, conv 22160, tr 4352)
  __shared__ float red[4];
  cg::grid_group grid = cg::this_grid();
  int tid = threadIdx.x;
  int nb = gridDim.x;

  // ---- P0: prep (weights T, bias, x cvt): 9217 tasks ----
  for (int t = blockIdx.x; t < 9217; t += nb) {
    if (t < 1024) {
      wtr_task(smem, tid, t, P.Wq, P.Wk, P.Wv, P.Wo, P.wT);
    } else if (t == 1024) {
      for (int j = tid; j < 3072; j += 256) {
        float v = 0.0f;
        if (j < 1024) v = P.bq[j];
        else if (j >= 2048) v = P.bv[j - 2048];
        P.qkvb[j] = v;
      }
    } else {
      int i = (t - 1025) * 1024 + tid * 4;
      float4 v = *(const float4*)&P.x[i];
      ushort4 o;
      o.x = f2bf(v.x); o.y = f2bf(v.y); o.z = f2bf(v.z); o.w = f2bf(v.w);
      *(ushort4*)&P.xb[i] = o;
    }
  }
  grid.sync();
  // ---- P1: QKV, 1536 tiles ----
  for (int t = blockIdx.x; t < 1536; t += nb) {
    int z = t >> 9, r = t & 511;
    gemm_tile<u16>(smem, tid, P.xb, 1024, P.wT + (size_t)z * 1048576u, 1024,
                   P.Qb + (long)z * 8388608, 1024,
                   (long)(r & 63) * 128, (long)(r >> 6) * 128, 1024, 1.0f,
                   P.qkvb + z * 1024, nullptr, 0);
  }
  grid.sync();
  // ---- P2: scores (1024) + V^T (2048) ----
  for (int t = blockIdx.x; t < 3072; t += nb) {
    if (t < 1024) {
      int z = t >> 8, r = t & 255;
      u16* C = (z < 2) ? P.Pd + (long)z * PBS : P.Pw + (long)(z - 2) * PBS;
      gemm_tile<u16>(smem, tid, P.Qb + (long)z * Sn * Dn, 1024,
                     P.Kb + (long)z * Sn * Dn, 1024, C, 2048,
                     (long)(r & 15) * 128, (long)((r >> 4) & 15) * 128,
                     1024, 0.03125f, nullptr, nullptr, 0);
    } else {
      vt_task(smem, tid, t - 1024, P.Vb, P.vt);
    }
  }
  grid.sync();
  // ---- P3: softmax (8192 rows) + conv (1024; Vb free after P2) ----
  for (int t = blockIdx.x; t < 9216; t += nb) {
    if (t < 8192) {
      u16* p = (t < 4096) ? P.Pd + (long)t * 2048 : P.Pw + (long)(t - 4096) * 2048;
      softmax_row(p, tid, red);
    } else {
      conv_task(smem, tid, t - 8192, P.x, P.cw, P.cb, P.conv);
    }
  }
  grid.sync();
  // ---- P4: PV (512) + LN(conv) in place (8192) ----
  for (int t = blockIdx.x; t < 8704; t += nb) {
    if (t < 512) {
      int z = t >> 7, r = t & 127;
      const u16* A = (z < 2) ? P.Pd + (long)z * PBS : P.Pw + (long)(z - 2) * PBS;
      gemm_tile<u16>(smem, tid, A, 2048, P.vt + (long)z * Dn * Sn, 2048,
                     P.attn + (long)z * Sn * Dn, 1024,
                     (long)(r & 15) * 128, (long)((r >> 4) & 7) * 128,
                     2048, 1.0f, nullptr, nullptr, 0);
    } else {
      ln_row(P.conv, nullptr, P.gamma, P.beta, P.conv, t - 512, tid, red);
    }
  }
  grid.sync();
  // ---- P5: combined = LN(conv + attn), 8192 rows ----
  for (int t = blockIdx.x; t < 8192; t += nb)
    ln_row(P.conv, P.attn, P.gamma, P.beta, P.combined, t, tid, red);
  grid.sync();
  // ---- P6: out = combined @ Wo + bo + x, 512 tiles ----
  for (int t = blockIdx.x; t < 512; t += nb)
    gemm_tile<float>(smem, tid, P.combined, 1024, P.wT + 3u * 1048576u, 1024,
                     P.out, 1024, (long)(t & 63) * 128, (long)(t >> 6) * 128,
                     1024, 1.0f, P.bo, P.x, 1024);
}

// ================= fallback kernels (round-9 proven path) =================
__global__ __launch_bounds__(256)
void prep_all(const float* Wq, const float* Wk, const float* Wv, const float* Wo,
              u16* wT, const float* bq, const float* bv, float* qkvb,
              const float* x, u16* xb) {
  __shared__ u16 sm[4352];
  int blk = blockIdx.x, tid = threadIdx.x;
  if (blk < 1024) {
    wtr_task(sm, tid, blk, Wq, Wk, Wv, Wo, wT);
  } else if (blk == 1024) {
    for (int j = tid; j < 3072; j += 256) {
      float v = 0.0f;
      if (j < 1024) v = bq[j];
      else if (j >= 2048) v = bv[j - 2048];
      qkvb[j] = v;
    }
  } else {
    int i = (blk - 1025) * 1024 + tid * 4;
    float4 v = *(const float4*)&x[i];
    ushort4 o;
    o.x = f2bf(v.x); o.y = f2bf(v.y); o.z = f2bf(v.z); o.w = f2bf(v.w);
    *(ushort4*)&xb[i] = o;
  }
}

template<typename CT>
__global__ __launch_bounds__(256, 2)
void gemm_nt(const u16* A, const u16* A2, long Abs, int lda,
             const u16* B, long Bbs, int ldb,
             CT* C, CT* C2, long Cbs, int ldc,
             int zsplit, int K, float scale,
             const float* bias, int bias_bs,
             const float* res, long Rbs, int ldr) {
  __shared__ u16 sm[16384];
  int z = blockIdx.z;
  if (z >= zsplit) { A = A2 + (long)(z - zsplit) * Abs; C = C2 + (long)(z - zsplit) * Cbs; }
  else             { A = A  + (long)z * Abs;            C = C  + (long)z * Cbs; }
  gemm_tile<CT>(sm, threadIdx.x, A, lda, B + (long)z * Bbs, ldb, C, ldc,
                (long)blockIdx.x * 128, (long)blockIdx.y * 128, K, scale,
                bias ? bias + (long)z * bias_bs : nullptr,
                res ? res + (long)z * Rbs : nullptr, ldr);
}

__global__ __launch_bounds__(256, 2)
void post_qkv(int ngemm, const u16* Qb, const u16* Kb,
              u16* Pd, u16* Pw, const u16* Vb, u16* vt) {
  __shared__ u16 sm[16384];
  int blk = blockIdx.x, tid = threadIdx.x;
  if (blk < ngemm) {
    int z = blk >> 8, r = blk & 255;
    u16* C = (z < 2) ? Pd + (long)z * PBS : Pw + (long)(z - 2) * PBS;
    gemm_tile<u16>(sm, tid, Qb + (long)z * Sn * Dn, 1024,
                   Kb + (long)z * Sn * Dn, 1024, C, 2048,
                   (long)(r & 15) * 128, (long)((r >> 4) & 15) * 128,
                   1024, 0.03125f, nullptr, nullptr, 0);
  } else {
    vt_task(sm, tid, blk - ngemm, Vb, vt);
  }
}

__global__ __launch_bounds__(256)
void smax_conv(u16* pa, u16* pb, int rowsplit, int nsm,
               const float* x, const float* cw, const float* cb, u16* convo) {
  __shared__ u16 smem[22168];
  __shared__ float red[4];
  int blk = blockIdx.x, tid = threadIdx.x;
  if (blk < nsm) {
    u16* p = (blk < rowsplit) ? pa + (long)blk * 2048 : pb + (long)(blk - rowsplit) * 2048;
    softmax_row(p, tid, red);
  } else {
    conv_task(smem, tid, blk - nsm, x, cw, cb, convo);
  }
}

__global__ __launch_bounds__(256, 2)
void pv_ln(int npv, const u16* Pd, const u16* Pw, const u16* vt, u16* attn,
           u16* conv, const float* gamma, const float* beta) {
  __shared__ u16 sm[16384];
  __shared__ float red[4];
  int blk = blockIdx.x, tid = threadIdx.x;
  if (blk < npv) {
    int z = blk >> 7, r = blk & 127;
    const u16* A = (z < 2) ? Pd + (long)z * PBS : Pw + (long)(z - 2) * PBS;
    gemm_tile<u16>(sm, tid, A, 2048, vt + (long)z * Dn * Sn, 2048,
                   attn + (long)z * Sn * Dn, 1024,
                   (long)(r & 15) * 128, (long)((r >> 4) & 7) * 128,
                   2048, 1.0f, nullptr, nullptr, 0);
  } else {
    ln_row(conv, nullptr, gamma, beta, conv, blk - npv, tid, red);
  }
}

__global__ __launch_bounds__(256)
void ln_kernel(const u16* a, const u16* b2, const float* gamma,
               const float* beta, u16* out) {
  __shared__ float red[4];
  ln_row(a, b2, gamma, beta, out, blockIdx.x, threadIdx.x, red);
}

// ================= workspace layout =================
static const size_t OFF_WT   = 0;
static const size_t OFF_QKVB = 8ull << 20;
static const size_t OFF_Q    = 9ull << 20;
static const size_t OFF_K    = 25ull << 20;
static const size_t OFF_V    = 41ull << 20;
static const size_t OFF_PW   = 57ull << 20;

extern "C" void kernel_launch(void* const* d_in, const int* in_sizes, int n_in,
                              void* d_out, int out_size, void* d_ws, size_t ws_size,
                              hipStream_t stream) {
  const float* x     = (const float*)d_in[0];
  const float* Wq    = (const float*)d_in[1];
  const float* bq    = (const float*)d_in[2];
  const float* Wk    = (const float*)d_in[3];
  const float* Wv    = (const float*)d_in[4];
  const float* bv    = (const float*)d_in[5];
  const float* cw    = (const float*)d_in[6];
  const float* cb    = (const float*)d_in[7];
  const float* gamma = (const float*)d_in[8];
  const float* beta  = (const float*)d_in[9];
  const float* Wo    = (const float*)d_in[10];
  const float* bo    = (const float*)d_in[11];
  float* out = (float*)d_out;
  char* ws = (char*)d_ws;

  u16*   wT    = (u16*)(ws + OFF_WT);
  float* qkvb  = (float*)(ws + OFF_QKVB);
  u16*   Qb    = (u16*)(ws + OFF_Q);
  u16*   Kb    = (u16*)(ws + OFF_K);
  u16*   Vb    = (u16*)(ws + OFF_V);
  u16*   Pw    = (u16*)(ws + OFF_PW);
  u16*   xb    = (u16*)d_out;
  u16*   Pd    = (u16*)d_out;
  u16*   vt    = (u16*)d_out + 8388608;
  u16*   conv  = Vb;
  u16*   attn  = Qb;
  u16*   combined = Kb;

  dim3 tb(256);

  hipError_t cerr = hipErrorUnknown;
  if (ws_size >= (73ull << 20)) {
    MegaP P{x, Wq, bq, Wk, Wv, bv, cw, cb, gamma, beta, Wo, bo,
            wT, qkvb, Qb, Kb, Vb, Pw, xb, Pd, vt, conv, attn, combined, out};
    void* args[] = { &P };
    cerr = hipLaunchCooperativeKernel((const void*)mega, dim3(768), tb, args, 0, stream);
  }
  if (cerr == hipSuccess) return;

  // -------- fallback: round-9 7-launch path --------
  prep_all<<<dim3(9217), tb, 0, stream>>>(Wq, Wk, Wv, Wo, wT, bq, bv, qkvb, x, xb);
  gemm_nt<u16><<<dim3(64, 8, 3), tb, 0, stream>>>(
      xb, nullptr, 0, 1024, wT, 1048576, 1024, Qb, (u16*)nullptr, 8388608, 1024,
      99, 1024, 1.0f, qkvb, 1024, nullptr, 0, 0);
  if (ws_size >= (73ull << 20)) {
    post_qkv<<<dim3(1024 + 2048), tb, 0, stream>>>(1024, Qb, Kb, Pd, Pw, Vb, vt);
    smax_conv<<<dim3(8192 + 1024), tb, 0, stream>>>(Pd, Pw, 4096, 8192, x, cw, cb, conv);
    pv_ln<<<dim3(512 + 8192), tb, 0, stream>>>(512, Pd, Pw, vt, attn, conv, gamma, beta);
  } else {
    post_qkv<<<dim3(2048), tb, 0, stream>>>(0, Qb, Kb, Pd, Pw, Vb, vt);
    for (int c = 0; c < 2; c++) {
      long off = (long)c * 2 * Sn * Dn;
      gemm_nt<u16><<<dim3(16, 16, 2), tb, 0, stream>>>(
          Qb + off, nullptr, (long)Sn * Dn, 1024, Kb + off, (long)Sn * Dn, 1024,
          Pd, (u16*)nullptr, PBS, 2048, 99, 1024, 0.03125f, nullptr, 0, nullptr, 0, 0);
      smax_conv<<<dim3(4096 + (c == 0 ? 1024 : 0)), tb, 0, stream>>>(
          Pd, Pd, 4096, 4096, x, cw, cb, conv);
      gemm_nt<u16><<<dim3(16, 8, 2), tb, 0, stream>>>(
          Pd, nullptr, PBS, 2048, vt + off, (long)Dn * Sn, 2048,
          attn + off, (u16*)nullptr, (long)Sn * Dn, 1024,
          99, 2048, 1.0f, nullptr, 0, nullptr, 0, 0);
    }
    ln_kernel<<<dim3(8192), tb, 0, stream>>>(conv, nullptr, gamma, beta, conv);
  }
  ln_kernel<<<dim3(8192), tb, 0, stream>>>(conv, attn, gamma, beta, combined);
  gemm_nt<float><<<dim3(64, 8, 1), tb, 0, stream>>>(
      combined, nullptr, 0, 1024, wT + 3u * 1048576u, 0, 1024,
      out, (float*)nullptr, 0, 1024, 99, 1024, 1.0f, bo, 0, x, 0, 1024);
}

// Round 11
// 355.818 us; speedup vs baseline: 2.6367x; 2.6367x over previous
//
#include <hip/hip_runtime.h>
#include <cstdint>

// DynamicConvAttention: B=4, S=2048, D=1024, NH=16 (groups), K=3
// f32 I/O, bf16 MFMA internal. 7 launches (primary path).
// == Round-9 proven structure (356 us). Round-10 cooperative mega-kernel
// == regressed 2.6x (min-occupancy imposed on latency-bound phases); reverted.
//
// ws (73 MB primary path):
//   wT   [0, 8 MB)      bf16 WqT,WkT,WvT,WoT (1M u16 each)
//   qkvb [8 MB, +12 KB) f32 concat bias [bq|0|bv]
//   Q    [9, 25 MB)  bf16 [8192][1024]  (attn overwrites after scores)
//   K    [25, 41 MB) bf16               (combined after scores)
//   V    [41, 57 MB) bf16               (conv output AFTER V->vt completes)
//   Pw   [57, 73 MB) bf16 P batches 2,3 (4096 rows)
// d_out (33.5 MB f32) as scratch:
//   xb = d_out[0:16.78MB)    bf16 x (dead after QKV) -> then P batches 0,1
//   vt = d_out[+8388608 u16] bf16 V^T [4][1024][2048] (dead after PV)
//
// ORDERING: conv output lives in Vb, so conv runs only AFTER V^T has
// consumed V (rides the softmax launch). LN(conv) rides the PV launch.

#define DEV __device__ __forceinline__

typedef unsigned short u16;
typedef __attribute__((ext_vector_type(8))) short bf16x8;
typedef __attribute__((ext_vector_type(4))) float f32x4;

static const int Sn = 2048, Dn = 1024;

DEV float bf2f(u16 u) { union { unsigned int i; float f; } w; w.i = ((unsigned int)u) << 16; return w.f; }
DEV u16 f2bf(float f) {
  union { float f; unsigned int i; } w; w.f = f;
  unsigned int x = w.i;
  return (u16)((x + 0x7FFFu + ((x >> 16) & 1u)) >> 16);
}

DEV void gload_lds16(const u16* gsrc, u16* lds_dst) {
  __builtin_amdgcn_global_load_lds(
      (const __attribute__((address_space(1))) void*)gsrc,
      (__attribute__((address_space(3))) void*)lds_dst,
      16, 0, 0);
}

DEV float block_allreduce_sum(float v, float* red, int tid) {
  #pragma unroll
  for (int o = 32; o > 0; o >>= 1) v += __shfl_down(v, o, 64);
  __syncthreads();
  if ((tid & 63) == 0) red[tid >> 6] = v;
  __syncthreads();
  return red[0] + red[1] + red[2] + red[3];
}

DEV float block_allreduce_max(float v, float* red, int tid) {
  #pragma unroll
  for (int o = 32; o > 0; o >>= 1) v = fmaxf(v, __shfl_down(v, o, 64));
  __syncthreads();
  if ((tid & 63) == 0) red[tid >> 6] = v;
  __syncthreads();
  return fmaxf(fmaxf(red[0], red[1]), fmaxf(red[2], red[3]));
}

// ---- layernorm row body (torch-style: ddof=1, eps on std); in-place safe ----
DEV void ln_row(const u16* __restrict__ a, const u16* __restrict__ b2,
                const float* __restrict__ gamma, const float* __restrict__ beta,
                u16* __restrict__ out, long row, int tid, float* red) {
  long base = row * Dn + tid * 4;
  ushort4 av = *(const ushort4*)&a[base];
  float v0 = bf2f(av.x), v1 = bf2f(av.y), v2 = bf2f(av.z), v3 = bf2f(av.w);
  if (b2) {
    ushort4 bv4 = *(const ushort4*)&b2[base];
    v0 += bf2f(bv4.x); v1 += bf2f(bv4.y); v2 += bf2f(bv4.z); v3 += bf2f(bv4.w);
  }
  float s = block_allreduce_sum(v0 + v1 + v2 + v3, red, tid);
  float mean = s * (1.0f / 1024.0f);
  float d0 = v0 - mean, d1 = v1 - mean, d2 = v2 - mean, d3 = v3 - mean;
  float sq = block_allreduce_sum(d0 * d0 + d1 * d1 + d2 * d2 + d3 * d3, red, tid);
  float inv = 1.0f / (sqrtf(sq * (1.0f / 1023.0f)) + 1e-6f);
  float4 gv = *(const float4*)&gamma[tid * 4];
  float4 bev = *(const float4*)&beta[tid * 4];
  ushort4 o;
  o.x = f2bf(gv.x * d0 * inv + bev.x);
  o.y = f2bf(gv.y * d1 * inv + bev.y);
  o.z = f2bf(gv.z * d2 * inv + bev.z);
  o.w = f2bf(gv.w * d3 * inv + bev.w);
  *(ushort4*)&out[base] = o;
}

// ================= prep_all: weights T + bias + x cvt ==============
// blocks [0,1024)    : weight transpose+cvt (4 weights x 256 tiles 64x64)
// block  1024        : qkv bias concat
// blocks [1025,9217) : x f32->bf16 (1024 elems each)
__global__ __launch_bounds__(256)
void prep_all(const float* __restrict__ Wq, const float* __restrict__ Wk,
              const float* __restrict__ Wv, const float* __restrict__ Wo,
              u16* __restrict__ wT,
              const float* __restrict__ bq, const float* __restrict__ bv,
              float* __restrict__ qkvb,
              const float* __restrict__ x, u16* __restrict__ xb) {
  __shared__ u16 sm[64][68];
  int blk = blockIdx.x;
  int tid = threadIdx.x;
  if (blk < 1024) {
    int w = blk >> 8, t = blk & 255;
    const float* src = (w == 0) ? Wq : (w == 1) ? Wk : (w == 2) ? Wv : Wo;
    u16* dst = wT + (size_t)w * 1048576u;
    int i0 = (t >> 4) << 6, j0 = (t & 15) << 6;
    int tx = tid & 15, r0 = tid >> 4;
    #pragma unroll
    for (int rr = r0; rr < 64; rr += 16) {
      float4 v = *(const float4*)&src[(long)(i0 + rr) * 1024 + j0 + tx * 4];
      sm[rr][tx*4+0] = f2bf(v.x); sm[rr][tx*4+1] = f2bf(v.y);
      sm[rr][tx*4+2] = f2bf(v.z); sm[rr][tx*4+3] = f2bf(v.w);
    }
    __syncthreads();
    #pragma unroll
    for (int cc = r0; cc < 64; cc += 16) {
      ushort4 o;
      o.x = sm[tx*4+0][cc]; o.y = sm[tx*4+1][cc];
      o.z = sm[tx*4+2][cc]; o.w = sm[tx*4+3][cc];
      *(ushort4*)&dst[(long)(j0 + cc) * 1024 + i0 + tx * 4] = o;
    }
  } else if (blk == 1024) {
    for (int j = tid; j < 3072; j += 256) {
      float v = 0.0f;
      if (j < 1024) v = bq[j];
      else if (j >= 2048) v = bv[j - 2048];
      qkvb[j] = v;
    }
  } else {
    int i = (blk - 1025) * 1024 + tid * 4;
    float4 v = *(const float4*)&x[i];
    ushort4 o;
    o.x = f2bf(v.x); o.y = f2bf(v.y); o.z = f2bf(v.z); o.w = f2bf(v.w);
    *(ushort4*)&xb[i] = o;
  }
}

// ================= NT GEMM, BK=64 split-halves (proven r7 core) ============
template<typename CT>
__global__ __launch_bounds__(256, 2)
void gemm_nt(const u16* __restrict__ A, const u16* __restrict__ A2, long Abs, int lda,
             const u16* __restrict__ B, long Bbs, int ldb,
             CT* __restrict__ C, CT* __restrict__ C2, long Cbs, int ldc,
             int zsplit, int K, float scale,
             const float* __restrict__ bias, int bias_bs,
             const float* __restrict__ res, long Rbs, int ldr) {
  __shared__ u16 sA[2][128 * 32];
  __shared__ u16 sB[2][128 * 32];
  int tid = threadIdx.x;
  int lane = tid & 63, wv = tid >> 6;
  int quad = lane >> 4, lm = lane & 15;
  int wr = wv >> 1, wc = wv & 1;
  long m0 = (long)blockIdx.x * 128, n0 = (long)blockIdx.y * 128;
  int z = blockIdx.z;
  if (z >= zsplit) { A = A2 + (long)(z - zsplit) * Abs; C = C2 + (long)(z - zsplit) * Cbs; }
  else             { A = A  + (long)z * Abs;            C = C  + (long)z * Cbs; }
  B += (long)z * Bbs;
  if (res) res += (long)z * Rbs;

  f32x4 acc[4][4] = {};

  int srow = wv * 16 + (lane >> 2);
  int sch = (lane & 3) * 8;
  const u16* Ap = A + (m0 + srow) * (long)lda + sch;
  const u16* Bp = B + (n0 + srow) * (long)ldb + sch;
  const int lofs = wv * 16 * 32;

  for (int k0 = 0; k0 < K; k0 += 64) {
    #pragma unroll
    for (int h = 0; h < 2; h++) {
      int kh = k0 + h * 32;
      gload_lds16(Ap + kh, &sA[h][lofs]);
      gload_lds16(Ap + 64 * (long)lda + kh, &sA[h][lofs + 64 * 32]);
      gload_lds16(Bp + kh, &sB[h][lofs]);
      gload_lds16(Bp + 64 * (long)ldb + kh, &sB[h][lofs + 64 * 32]);
    }
    __syncthreads();
    #pragma unroll
    for (int h = 0; h < 2; h++) {
      bf16x8 af[4], bfr[4];
      #pragma unroll
      for (int mi = 0; mi < 4; mi++)
        af[mi] = *(const bf16x8*)&sA[h][(wr * 64 + mi * 16 + lm) * 32 + quad * 8];
      #pragma unroll
      for (int ni = 0; ni < 4; ni++)
        bfr[ni] = *(const bf16x8*)&sB[h][(wc * 64 + ni * 16 + lm) * 32 + quad * 8];
      #pragma unroll
      for (int mi = 0; mi < 4; mi++)
        #pragma unroll
        for (int ni = 0; ni < 4; ni++)
          acc[mi][ni] = __builtin_amdgcn_mfma_f32_16x16x32_bf16(af[mi], bfr[ni], acc[mi][ni], 0, 0, 0);
    }
    __syncthreads();
  }

  #pragma unroll
  for (int mi = 0; mi < 4; mi++) {
    #pragma unroll
    for (int ni = 0; ni < 4; ni++) {
      int col = (int)n0 + wc * 64 + ni * 16 + lm;
      float bv = bias ? bias[(long)z * bias_bs + col] : 0.0f;
      #pragma unroll
      for (int r = 0; r < 4; r++) {
        long rowg = m0 + wr * 64 + mi * 16 + quad * 4 + r;
        float v = acc[mi][ni][r] * scale + bv;
        if (res) v += res[rowg * (long)ldr + col];
        if constexpr (sizeof(CT) == 2) C[rowg * (long)ldc + col] = f2bf(v);
        else                           C[rowg * (long)ldc + col] = v;
      }
    }
  }
}

// ============ post_qkv: scores GEMM + V^T transpose, one launch ============
// blocks [0, ngemm)          : scores tile (bx=r&15, by=(r>>4)&15, z=r>>8)
// blocks [ngemm, ngemm+2048) : V^T 64x64 tiles
__global__ __launch_bounds__(256, 2)
void post_qkv(int ngemm,
              const u16* __restrict__ Qb, const u16* __restrict__ Kb,
              u16* __restrict__ Pd, u16* __restrict__ Pw,
              const u16* __restrict__ Vb, u16* __restrict__ vt) {
  __shared__ u16 smem[2 * 2 * 128 * 32];  // 32 KB
  int blk = blockIdx.x;
  int tid = threadIdx.x;
  if (blk < ngemm) {
    u16* sA0 = smem;
    u16* sB0 = smem + 2 * 128 * 32;
    int lane = tid & 63, wv = tid >> 6;
    int quad = lane >> 4, lm = lane & 15;
    int wr = wv >> 1, wc = wv & 1;
    int z = blk >> 8;
    long m0 = (long)(blk & 15) * 128, n0 = (long)((blk >> 4) & 15) * 128;
    const u16* A = Qb + (long)z * Sn * Dn;
    const u16* B = Kb + (long)z * Sn * Dn;
    u16* C = (z < 2) ? Pd + (long)z * Sn * Sn : Pw + (long)(z - 2) * Sn * Sn;

    f32x4 acc[4][4] = {};
    int srow = wv * 16 + (lane >> 2);
    int sch = (lane & 3) * 8;
    const u16* Ap = A + (m0 + srow) * 1024 + sch;
    const u16* Bp = B + (n0 + srow) * 1024 + sch;
    const int lofs = wv * 16 * 32;

    for (int k0 = 0; k0 < 1024; k0 += 64) {
      #pragma unroll
      for (int h = 0; h < 2; h++) {
        int kh = k0 + h * 32;
        gload_lds16(Ap + kh, &sA0[h * 128 * 32 + lofs]);
        gload_lds16(Ap + 64 * 1024 + kh, &sA0[h * 128 * 32 + lofs + 64 * 32]);
        gload_lds16(Bp + kh, &sB0[h * 128 * 32 + lofs]);
        gload_lds16(Bp + 64 * 1024 + kh, &sB0[h * 128 * 32 + lofs + 64 * 32]);
      }
      __syncthreads();
      #pragma unroll
      for (int h = 0; h < 2; h++) {
        bf16x8 af[4], bfr[4];
        #pragma unroll
        for (int mi = 0; mi < 4; mi++)
          af[mi] = *(const bf16x8*)&sA0[h * 128 * 32 + (wr * 64 + mi * 16 + lm) * 32 + quad * 8];
        #pragma unroll
        for (int ni = 0; ni < 4; ni++)
          bfr[ni] = *(const bf16x8*)&sB0[h * 128 * 32 + (wc * 64 + ni * 16 + lm) * 32 + quad * 8];
        #pragma unroll
        for (int mi = 0; mi < 4; mi++)
          #pragma unroll
          for (int ni = 0; ni < 4; ni++)
            acc[mi][ni] = __builtin_amdgcn_mfma_f32_16x16x32_bf16(af[mi], bfr[ni], acc[mi][ni], 0, 0, 0);
      }
      __syncthreads();
    }
    #pragma unroll
    for (int mi = 0; mi < 4; mi++) {
      #pragma unroll
      for (int ni = 0; ni < 4; ni++) {
        int col = (int)n0 + wc * 64 + ni * 16 + lm;
        #pragma unroll
        for (int r = 0; r < 4; r++) {
          long rowg = m0 + wr * 64 + mi * 16 + quad * 4 + r;
          C[rowg * 2048 + col] = f2bf(acc[mi][ni][r] * 0.03125f);
        }
      }
    }
  } else {
    u16 (*sm)[68] = (u16(*)[68])smem;
    int t = blk - ngemm;
    int b = t >> 9, r = t & 511;
    int j0 = (r & 15) << 6, i0 = ((r >> 4) & 31) << 6;
    const u16* s = Vb + (long)b * Sn * Dn;
    u16* d = vt + (long)b * Dn * Sn;
    int tx = tid & 15, r0 = tid >> 4;
    #pragma unroll
    for (int rr = r0; rr < 64; rr += 16) {
      ushort4 v = *(const ushort4*)&s[(long)(i0 + rr) * 1024 + j0 + tx * 4];
      sm[rr][tx*4+0] = v.x; sm[rr][tx*4+1] = v.y; sm[rr][tx*4+2] = v.z; sm[rr][tx*4+3] = v.w;
    }
    __syncthreads();
    #pragma unroll
    for (int cc = r0; cc < 64; cc += 16) {
      ushort4 o;
      o.x = sm[tx*4+0][cc]; o.y = sm[tx*4+1][cc];
      o.z = sm[tx*4+2][cc]; o.w = sm[tx*4+3][cc];
      *(ushort4*)&d[(long)(j0 + cc) * 2048 + i0 + tx * 4] = o;
    }
  }
}

// ============ smax_conv: softmax rows + grouped conv (V dead -> Vb free) ===
// blocks [0, nsm)           : softmax row (split pa/pb at rowsplit)
// blocks [nsm, nsm + nconv) : conv via MFMA, reads x & cw (f32) directly
__global__ __launch_bounds__(256)
void smax_conv(u16* __restrict__ pa, u16* __restrict__ pb, int rowsplit, int nsm,
               const float* __restrict__ x, const float* __restrict__ cw,
               const float* __restrict__ cb, u16* __restrict__ convo) {
  __shared__ u16 smem[22160];  // conv: sx 130x72 (9360 u16) + sw 64x200 (12800 u16)
  __shared__ float red[4];
  int blk = blockIdx.x;
  int tid = threadIdx.x;
  if (blk < nsm) {
    long row = blk;
    u16* p = (row < rowsplit) ? pa + row * 2048 : pb + (row - rowsplit) * 2048;
    ushort4 a = *(const ushort4*)&p[tid * 8];
    ushort4 b = *(const ushort4*)&p[tid * 8 + 4];
    float f0 = bf2f(a.x), f1 = bf2f(a.y), f2 = bf2f(a.z), f3 = bf2f(a.w);
    float f4 = bf2f(b.x), f5 = bf2f(b.y), f6 = bf2f(b.z), f7 = bf2f(b.w);
    float m = fmaxf(fmaxf(fmaxf(f0, f1), fmaxf(f2, f3)),
                    fmaxf(fmaxf(f4, f5), fmaxf(f6, f7)));
    m = block_allreduce_max(m, red, tid);
    float e0 = __expf(f0 - m), e1 = __expf(f1 - m), e2 = __expf(f2 - m), e3 = __expf(f3 - m);
    float e4 = __expf(f4 - m), e5 = __expf(f5 - m), e6 = __expf(f6 - m), e7 = __expf(f7 - m);
    float s = block_allreduce_sum(e0 + e1 + e2 + e3 + e4 + e5 + e6 + e7, red, tid);
    float inv = 1.0f / s;
    ushort4 o1, o2;
    o1.x = f2bf(e0 * inv); o1.y = f2bf(e1 * inv); o1.z = f2bf(e2 * inv); o1.w = f2bf(e3 * inv);
    o2.x = f2bf(e4 * inv); o2.y = f2bf(e5 * inv); o2.z = f2bf(e6 * inv); o2.w = f2bf(e7 * inv);
    *(ushort4*)&p[tid * 8] = o1;
    *(ushort4*)&p[tid * 8 + 4] = o2;
  } else {
    // conv: out[s,oc] = cb[oc] + sum_k x[s+t-1, g*64+i]*w[oc, k=t*64+i]
    u16 (*sx)[72] = (u16(*)[72])smem;
    u16 (*sw)[200] = (u16(*)[200])(smem + 9360);
    int r = blk - nsm;
    int s0 = (r & 15) * 128;
    int g = (r >> 4) & 15;
    int b = r >> 8;
    int lane = tid & 63, wv = tid >> 6;
    int quad = lane >> 4, lm = lane & 15;
    for (int idx = tid; idx < 64 * 192; idx += 256) {
      int oc = idx / 192, k = idx - oc * 192;
      int t = k >> 6, i = k & 63;
      sw[oc][k] = f2bf(cw[((long)(g * 64 + oc)) * 192 + i * 3 + t]);
    }
    for (int idx = tid; idx < 130 * 16; idx += 256) {
      int rr = idx >> 4, c4 = (idx & 15) * 4;
      int s = s0 - 1 + rr;
      ushort4 v;
      if (s >= 0 && s < Sn) {
        float4 f = *(const float4*)&x[((long)b * Sn + s) * Dn + g * 64 + c4];
        v.x = f2bf(f.x); v.y = f2bf(f.y); v.z = f2bf(f.z); v.w = f2bf(f.w);
      } else { v.x = 0; v.y = 0; v.z = 0; v.w = 0; }
      *(ushort4*)&sx[rr][c4] = v;
    }
    __syncthreads();
    f32x4 acc[2][4] = {};
    #pragma unroll
    for (int ks = 0; ks < 6; ks++) {
      int t = ks >> 1;
      int i0 = (ks & 1) * 32 + quad * 8;
      bf16x8 a0 = *(const bf16x8*)&sx[wv * 32 + lm + t][i0];
      bf16x8 a1 = *(const bf16x8*)&sx[wv * 32 + 16 + lm + t][i0];
      #pragma unroll
      for (int nf = 0; nf < 4; nf++) {
        bf16x8 bf = *(const bf16x8*)&sw[nf * 16 + lm][ks * 32 + quad * 8];
        acc[0][nf] = __builtin_amdgcn_mfma_f32_16x16x32_bf16(a0, bf, acc[0][nf], 0, 0, 0);
        acc[1][nf] = __builtin_amdgcn_mfma_f32_16x16x32_bf16(a1, bf, acc[1][nf], 0, 0, 0);
      }
    }
    #pragma unroll
    for (int mi = 0; mi < 2; mi++) {
      #pragma unroll
      for (int nf = 0; nf < 4; nf++) {
        int col = g * 64 + nf * 16 + lm;
        float bias = cb[col];
        #pragma unroll
        for (int rr = 0; rr < 4; rr++) {
          int row = wv * 32 + mi * 16 + quad * 4 + rr;
          convo[((long)b * Sn + s0 + row) * Dn + col] = f2bf(acc[mi][nf][rr] + bias);
        }
      }
    }
  }
}

// ============ pv_ln: PV GEMM (flattened) + LN(conv) in place ===============
// blocks [0, npv)         : PV tile (bx=r&15, by=(r>>4)&7, z=r>>7); K=2048
// blocks [npv, npv+8192)  : LN(conv) row, in place
__global__ __launch_bounds__(256, 2)
void pv_ln(int npv,
           const u16* __restrict__ Pd, const u16* __restrict__ Pw,
           const u16* __restrict__ vt, u16* __restrict__ attn,
           u16* __restrict__ conv,
           const float* __restrict__ gamma, const float* __restrict__ beta) {
  __shared__ u16 smem[2 * 2 * 128 * 32];  // 32 KB
  __shared__ float red[4];
  int blk = blockIdx.x;
  int tid = threadIdx.x;
  if (blk < npv) {
    u16* sA0 = smem;
    u16* sB0 = smem + 2 * 128 * 32;
    int lane = tid & 63, wv = tid >> 6;
    int quad = lane >> 4, lm = lane & 15;
    int wr = wv >> 1, wc = wv & 1;
    int z = blk >> 7;
    long m0 = (long)(blk & 15) * 128, n0 = (long)((blk >> 4) & 7) * 128;
    const u16* A = (z < 2) ? Pd + (long)z * Sn * Sn : Pw + (long)(z - 2) * Sn * Sn;
    const u16* B = vt + (long)z * Dn * Sn;
    u16* C = attn + (long)z * Sn * Dn;

    f32x4 acc[4][4] = {};
    int srow = wv * 16 + (lane >> 2);
    int sch = (lane & 3) * 8;
    const u16* Ap = A + (m0 + srow) * 2048 + sch;
    const u16* Bp = B + (n0 + srow) * 2048 + sch;
    const int lofs = wv * 16 * 32;

    for (int k0 = 0; k0 < 2048; k0 += 64) {
      #pragma unroll
      for (int h = 0; h < 2; h++) {
        int kh = k0 + h * 32;
        gload_lds16(Ap + kh, &sA0[h * 128 * 32 + lofs]);
        gload_lds16(Ap + 64 * 2048 + kh, &sA0[h * 128 * 32 + lofs + 64 * 32]);
        gload_lds16(Bp + kh, &sB0[h * 128 * 32 + lofs]);
        gload_lds16(Bp + 64 * 2048 + kh, &sB0[h * 128 * 32 + lofs + 64 * 32]);
      }
      __syncthreads();
      #pragma unroll
      for (int h = 0; h < 2; h++) {
        bf16x8 af[4], bfr[4];
        #pragma unroll
        for (int mi = 0; mi < 4; mi++)
          af[mi] = *(const bf16x8*)&sA0[h * 128 * 32 + (wr * 64 + mi * 16 + lm) * 32 + quad * 8];
        #pragma unroll
        for (int ni = 0; ni < 4; ni++)
          bfr[ni] = *(const bf16x8*)&sB0[h * 128 * 32 + (wc * 64 + ni * 16 + lm) * 32 + quad * 8];
        #pragma unroll
        for (int mi = 0; mi < 4; mi++)
          #pragma unroll
          for (int ni = 0; ni < 4; ni++)
            acc[mi][ni] = __builtin_amdgcn_mfma_f32_16x16x32_bf16(af[mi], bfr[ni], acc[mi][ni], 0, 0, 0);
      }
      __syncthreads();
    }
    #pragma unroll
    for (int mi = 0; mi < 4; mi++) {
      #pragma unroll
      for (int ni = 0; ni < 4; ni++) {
        int col = (int)n0 + wc * 64 + ni * 16 + lm;
        #pragma unroll
        for (int r = 0; r < 4; r++) {
          long rowg = m0 + wr * 64 + mi * 16 + quad * 4 + r;
          C[rowg * 1024 + col] = f2bf(acc[mi][ni][r]);
        }
      }
    }
  } else {
    long row = blk - npv;
    ln_row(conv, nullptr, gamma, beta, conv, row, tid, red);
  }
}

// ================= layernorm standalone =================
__global__ __launch_bounds__(256)
void ln_kernel(const u16* __restrict__ a, const u16* __restrict__ b2,
               const float* __restrict__ gamma, const float* __restrict__ beta,
               u16* __restrict__ out) {
  __shared__ float red[4];
  ln_row(a, b2, gamma, beta, out, blockIdx.x, threadIdx.x, red);
}

// ================= workspace layout =================
static const size_t OFF_WT    = 0;
static const size_t OFF_QKVB  = 8ull << 20;
static const size_t OFF_Q     = 9ull << 20;
static const size_t OFF_K     = 25ull << 20;
static const size_t OFF_V     = 41ull << 20;
static const size_t OFF_PW    = 57ull << 20;

extern "C" void kernel_launch(void* const* d_in, const int* in_sizes, int n_in,
                              void* d_out, int out_size, void* d_ws, size_t ws_size,
                              hipStream_t stream) {
  const float* x     = (const float*)d_in[0];
  const float* Wq    = (const float*)d_in[1];
  const float* bq    = (const float*)d_in[2];
  const float* Wk    = (const float*)d_in[3];
  const float* Wv    = (const float*)d_in[4];
  const float* bv    = (const float*)d_in[5];
  const float* cw    = (const float*)d_in[6];
  const float* cb    = (const float*)d_in[7];
  const float* gamma = (const float*)d_in[8];
  const float* beta  = (const float*)d_in[9];
  const float* Wo    = (const float*)d_in[10];
  const float* bo    = (const float*)d_in[11];
  float* out = (float*)d_out;
  char* ws = (char*)d_ws;

  u16*   wT    = (u16*)(ws + OFF_WT);
  float* qkvb  = (float*)(ws + OFF_QKVB);
  u16*   Qb    = (u16*)(ws + OFF_Q);
  u16*   Kb    = (u16*)(ws + OFF_K);
  u16*   Vb    = (u16*)(ws + OFF_V);
  u16*   Pw    = (u16*)(ws + OFF_PW);
  u16*   xb    = (u16*)d_out;               // dead after QKV; then P b0,1
  u16*   Pd    = (u16*)d_out;
  u16*   vt    = (u16*)d_out + 8388608;     // V^T, dead after PV
  u16*   conv  = Vb;                        // written only after V^T done
  u16*   attn  = Qb;
  u16*   combined = Kb;
  const long PBS = (long)Sn * Sn;

  dim3 tb(256);

  // 1. prologue: weights T + bias + x cvt
  prep_all<<<dim3(9217), tb, 0, stream>>>(Wq, Wk, Wv, Wo, wT, bq, bv, qkvb, x, xb);
  // 2. QKV (z = Q,K,V planes)
  gemm_nt<u16><<<dim3(64, 8, 3), tb, 0, stream>>>(
      xb, nullptr, 0, 1024, wT, 1048576, 1024, Qb, (u16*)nullptr, 8388608, 1024,
      99, 1024, 1.0f, qkvb, 1024, nullptr, 0, 0);

  if (ws_size >= (73ull << 20)) {
    // 3. scores GEMM + V^T (V consumed here; Vb free afterwards)
    post_qkv<<<dim3(1024 + 2048), tb, 0, stream>>>(1024, Qb, Kb, Pd, Pw, Vb, vt);
    // 4. softmax (8192 rows) + conv (1024 blocks) -> conv into Vb
    smax_conv<<<dim3(8192 + 1024), tb, 0, stream>>>(Pd, Pw, 4096, 8192,
                                                    x, cw, cb, conv);
    // 5. PV (512 tiles) + LN(conv) in place (8192 rows)
    pv_ln<<<dim3(512 + 8192), tb, 0, stream>>>(512, Pd, Pw, vt, attn, conv,
                                               gamma, beta);
  } else {
    // fallback: V^T only, then chunked attention; conv rides chunk-0 softmax
    post_qkv<<<dim3(2048), tb, 0, stream>>>(0, Qb, Kb, Pd, Pw, Vb, vt);
    for (int c = 0; c < 2; c++) {
      long off = (long)c * 2 * Sn * Dn;
      gemm_nt<u16><<<dim3(16, 16, 2), tb, 0, stream>>>(
          Qb + off, nullptr, (long)Sn * Dn, 1024, Kb + off, (long)Sn * Dn, 1024,
          Pd, (u16*)nullptr, PBS, 2048,
          99, 1024, 0.03125f, nullptr, 0, nullptr, 0, 0);
      smax_conv<<<dim3(4096 + (c == 0 ? 1024 : 0)), tb, 0, stream>>>(
          Pd, Pd, 4096, 4096, x, cw, cb, conv);
      gemm_nt<u16><<<dim3(16, 8, 2), tb, 0, stream>>>(
          Pd, nullptr, PBS, 2048, vt + off, (long)Dn * Sn, 2048,
          attn + off, (u16*)nullptr, (long)Sn * Dn, 1024,
          99, 2048, 1.0f, nullptr, 0, nullptr, 0, 0);
    }
    ln_kernel<<<dim3(8192), tb, 0, stream>>>(conv, nullptr, gamma, beta, conv);
  }

  // 6. combined = LN(conv + attn); 7. out = combined @ Wo + bo + x
  ln_kernel<<<dim3(8192), tb, 0, stream>>>(conv, attn, gamma, beta, combined);
  gemm_nt<float><<<dim3(64, 8, 1), tb, 0, stream>>>(
      combined, nullptr, 0, 1024, wT + 3u * 1048576u, 0, 1024,
      out, (float*)nullptr, 0, 1024,
      99, 1024, 1.0f, bo, 0, x, 0, 1024);
}